// Round 1
// 1783.124 us; speedup vs baseline: 6.5430x; 6.5430x over previous
//
#include <hip/hip_runtime.h>
#include <math.h>

// Problem constants (B=2, S=2048, D_MODEL=1024, H=16, DK=64)
#define MDIM 4096   // B*S rows
#define NDIM 1024
#define KDIM 1024
#define S_LEN 2048
#define NH 16
#define DK 64
#define KT 64
#define QT 64
#define NTILE (S_LEN / KT)   // 32

// ---------------------------------------------------------------------------
// GEMM NT: Y = A(M,K) @ W(N,K)^T + bias(N)   (unchanged, verified)
// ---------------------------------------------------------------------------
__global__ __launch_bounds__(256)
void gemm_nt_kernel(const float* __restrict__ A, const float* __restrict__ W,
                    const float* __restrict__ bias, float* __restrict__ Y,
                    int split_head)
{
    __shared__ float As[16][68];
    __shared__ float Ws[16][68];
    const int tid = threadIdx.x;
    const int m0 = blockIdx.y << 6;
    const int n0 = blockIdx.x << 6;
    const int tx = tid & 15;
    const int ty = tid >> 4;

    float acc[4][4] = {};

    for (int k0 = 0; k0 < KDIM; k0 += 16) {
        #pragma unroll
        for (int i = 0; i < 4; i++) {
            int e = tid + (i << 8);
            int r = e >> 4;
            int c = e & 15;
            As[c][r] = A[(m0 + r) * KDIM + k0 + c];
            Ws[c][r] = W[(n0 + r) * KDIM + k0 + c];
        }
        __syncthreads();
        #pragma unroll
        for (int kk = 0; kk < 16; kk++) {
            float a[4], w[4];
            #pragma unroll
            for (int i = 0; i < 4; i++) a[i] = As[kk][ty * 4 + i];
            #pragma unroll
            for (int j = 0; j < 4; j++) w[j] = Ws[kk][tx * 4 + j];
            #pragma unroll
            for (int i = 0; i < 4; i++)
                #pragma unroll
                for (int j = 0; j < 4; j++)
                    acc[i][j] += a[i] * w[j];
        }
        __syncthreads();
    }

    #pragma unroll
    for (int i = 0; i < 4; i++) {
        int m = m0 + ty * 4 + i;
        #pragma unroll
        for (int j = 0; j < 4; j++) {
            int n = n0 + tx * 4 + j;
            float val = acc[i][j] + bias[n];
            if (split_head) {
                int b = m >> 11, s = m & (S_LEN - 1);
                int h = n >> 6,  d = n & (DK - 1);
                Y[(((size_t)(b * NH + h) * S_LEN + s) << 6) + d] = val;
            } else {
                Y[(size_t)m * NDIM + n] = val;
            }
        }
    }
}

// ---------------------------------------------------------------------------
// Fused attention, LDS-tiled two-GEMM flash structure.
// Block = (b, h, 64 q-rows). 256 threads; thread (tx,ty) owns a 4x4 tile:
// rows ty*4+i, cols tx*4+j. Pass 1 computes online (m,l) per row via a
// 64x64x64 register-tiled GEMM; pass 2 recomputes S, writes normalized attn,
// stages P into LDS (reusing Ks), then PV GEMM into acc[4][4].
// ctx written in (B, S, H, DK) == (B, S, D_MODEL) layout for the out-proj.
// ---------------------------------------------------------------------------
__global__ __launch_bounds__(256, 3)
void attn_kernel(const float* __restrict__ q, const float* __restrict__ k,
                 const float* __restrict__ v, const int* __restrict__ mask,
                 float* __restrict__ attn, float* __restrict__ ctx)
{
    const int b   = blockIdx.z;
    const int h   = blockIdx.y;
    const int q0  = blockIdx.x << 6;
    const int tid = threadIdx.x;
    const int tx  = tid & 15;
    const int ty  = tid >> 4;

    __shared__ float Qs[64][68];   // [d][m]  (68: 16B-aligned rows, bank spread)
    __shared__ float Ks[64][68];   // [d][n]  -> reused as Ps[kk][m] after S-GEMM
    __shared__ float Vs[64][68];   // [kk][d]
    float* Ps = &Ks[0][0];

    const float* qbase = q + (((size_t)(b * NH + h) * S_LEN + q0) << 6);
    const float* kbase = k + (((size_t)(b * NH + h) * S_LEN) << 6);
    const float* vbase = v + (((size_t)(b * NH + h) * S_LEN) << 6);
    const int*   mrow  = mask + b * S_LEN;

    const int ln = tid & 63;   // row within 64-tile for staging
    const int dg = tid >> 6;   // wave id = 16-wide d-group for staging

    // ---- stage Q tile transposed: Qs[d][m]; conflict-free scalar writes ----
    {
        const float4* src = (const float4*)(qbase + ((size_t)ln << 6) + (dg << 4));
        #pragma unroll
        for (int c4 = 0; c4 < 4; c4++) {
            float4 t = src[c4];
            int d = (dg << 4) + (c4 << 2);
            Qs[d + 0][ln] = t.x; Qs[d + 1][ln] = t.y;
            Qs[d + 2][ln] = t.z; Qs[d + 3][ln] = t.w;
        }
    }
    // Qs visibility covered by the barrier inside the first tile iteration.

    const float scale = 0.125f;   // 1/sqrt(64)
    float mr[4], lr[4];
    #pragma unroll
    for (int i = 0; i < 4; i++) { mr[i] = -1e30f; lr[i] = 0.f; }

    // ==================== pass 1: softmax stats ====================
    for (int t = 0; t < NTILE; t++) {
        // issue-early: global loads into regs before the barrier
        float4 kr[4];
        {
            const float4* src = (const float4*)(kbase + (((size_t)(t << 6) + ln) << 6) + (dg << 4));
            #pragma unroll
            for (int c4 = 0; c4 < 4; c4++) kr[c4] = src[c4];
        }
        __syncthreads();   // previous iteration's Ks reads complete
        #pragma unroll
        for (int c4 = 0; c4 < 4; c4++) {
            int d = (dg << 4) + (c4 << 2);
            Ks[d + 0][ln] = kr[c4].x; Ks[d + 1][ln] = kr[c4].y;
            Ks[d + 2][ln] = kr[c4].z; Ks[d + 3][ln] = kr[c4].w;
        }
        __syncthreads();

        float s[4][4] = {};
        #pragma unroll 8
        for (int kk = 0; kk < 64; kk++) {
            float a[4], w[4];
            *(float4*)a = *(const float4*)&Qs[kk][ty << 2];   // broadcast across tx
            *(float4*)w = *(const float4*)&Ks[kk][tx << 2];
            #pragma unroll
            for (int i = 0; i < 4; i++)
                #pragma unroll
                for (int j = 0; j < 4; j++)
                    s[i][j] += a[i] * w[j];
        }

        int4 mk = ((const int4*)(mrow + (t << 6)))[tx];
        #pragma unroll
        for (int i = 0; i < 4; i++) {
            float s0 = (mk.x == 0) ? -1e9f : s[i][0] * scale;
            float s1 = (mk.y == 0) ? -1e9f : s[i][1] * scale;
            float s2 = (mk.z == 0) ? -1e9f : s[i][2] * scale;
            float s3 = (mk.w == 0) ? -1e9f : s[i][3] * scale;
            float mt = fmaxf(fmaxf(s0, s1), fmaxf(s2, s3));
            float mn = fmaxf(mr[i], mt);
            lr[i] = lr[i] * __expf(mr[i] - mn)
                  + __expf(s0 - mn) + __expf(s1 - mn)
                  + __expf(s2 - mn) + __expf(s3 - mn);
            mr[i] = mn;
        }
    }

    // combine across the 16 column-lanes (consecutive lanes, same wave)
    #pragma unroll
    for (int off = 1; off < 16; off <<= 1) {
        #pragma unroll
        for (int i = 0; i < 4; i++) {
            float m2 = __shfl_xor(mr[i], off);
            float l2 = __shfl_xor(lr[i], off);
            float mn = fmaxf(mr[i], m2);
            lr[i] = lr[i] * __expf(mr[i] - mn) + l2 * __expf(m2 - mn);
            mr[i] = mn;
        }
    }
    float invl[4];
    #pragma unroll
    for (int i = 0; i < 4; i++) invl[i] = 1.0f / lr[i];

    // ==================== pass 2: attn write + PV ====================
    float acc[4][4] = {};
    for (int t = 0; t < NTILE; t++) {
        float4 kr[4], vr[4];
        {
            const float4* src = (const float4*)(kbase + (((size_t)(t << 6) + ln) << 6) + (dg << 4));
            #pragma unroll
            for (int c4 = 0; c4 < 4; c4++) kr[c4] = src[c4];
        }
        #pragma unroll
        for (int i2 = 0; i2 < 4; i2++) {
            int slot = tid + (i2 << 8);
            int row = slot >> 4, c4 = slot & 15;
            vr[i2] = ((const float4*)(vbase + (((size_t)(t << 6) + row) << 6)))[c4];
        }
        __syncthreads();   // previous iteration's Ps/Vs reads complete
        #pragma unroll
        for (int c4 = 0; c4 < 4; c4++) {
            int d = (dg << 4) + (c4 << 2);
            Ks[d + 0][ln] = kr[c4].x; Ks[d + 1][ln] = kr[c4].y;
            Ks[d + 2][ln] = kr[c4].z; Ks[d + 3][ln] = kr[c4].w;
        }
        #pragma unroll
        for (int i2 = 0; i2 < 4; i2++) {
            int slot = tid + (i2 << 8);
            int row = slot >> 4, c4 = slot & 15;
            *(float4*)&Vs[row][c4 << 2] = vr[i2];
        }
        __syncthreads();

        float s[4][4] = {};
        #pragma unroll 8
        for (int kk = 0; kk < 64; kk++) {
            float a[4], w[4];
            *(float4*)a = *(const float4*)&Qs[kk][ty << 2];
            *(float4*)w = *(const float4*)&Ks[kk][tx << 2];
            #pragma unroll
            for (int i = 0; i < 4; i++)
                #pragma unroll
                for (int j = 0; j < 4; j++)
                    s[i][j] += a[i] * w[j];
        }

        int4 mk = ((const int4*)(mrow + (t << 6)))[tx];
        float p[4][4];
        #pragma unroll
        for (int i = 0; i < 4; i++) {
            float s0 = (mk.x == 0) ? -1e9f : s[i][0] * scale;
            float s1 = (mk.y == 0) ? -1e9f : s[i][1] * scale;
            float s2 = (mk.z == 0) ? -1e9f : s[i][2] * scale;
            float s3 = (mk.w == 0) ? -1e9f : s[i][3] * scale;
            p[i][0] = __expf(s0 - mr[i]) * invl[i];
            p[i][1] = __expf(s1 - mr[i]) * invl[i];
            p[i][2] = __expf(s2 - mr[i]) * invl[i];
            p[i][3] = __expf(s3 - mr[i]) * invl[i];
        }

        // coalesced attn store: float4 per row, 16 lanes -> 256B per row segment
        {
            size_t arow = ((size_t)((b * NH + h) * S_LEN + q0 + (ty << 2))) * S_LEN
                        + (t << 6) + (tx << 2);
            #pragma unroll
            for (int i = 0; i < 4; i++)
                *(float4*)(attn + arow + (size_t)i * S_LEN) =
                    make_float4(p[i][0], p[i][1], p[i][2], p[i][3]);
        }

        __syncthreads();   // all Ks reads done -> reuse buffer as Ps[kk][m]
        #pragma unroll
        for (int j = 0; j < 4; j++)
            *(float4*)&Ps[(size_t)((tx << 2) + j) * 68 + (ty << 2)] =
                make_float4(p[0][j], p[1][j], p[2][j], p[3][j]);
        __syncthreads();

        #pragma unroll 8
        for (int kk = 0; kk < 64; kk++) {
            float pa[4], wv[4];
            *(float4*)pa = *(const float4*)&Ps[(size_t)kk * 68 + (ty << 2)];  // broadcast
            *(float4*)wv = *(const float4*)&Vs[kk][tx << 2];
            #pragma unroll
            for (int i = 0; i < 4; i++)
                #pragma unroll
                for (int j = 0; j < 4; j++)
                    acc[i][j] += pa[i] * wv[j];
        }
    }

    // ctx write, (B, S, H, DK) layout
    #pragma unroll
    for (int i = 0; i < 4; i++) {
        int row = q0 + (ty << 2) + i;
        *(float4*)(ctx + (((size_t)(b * S_LEN + row) * NH + h) << 6) + (tx << 2)) =
            make_float4(acc[i][0], acc[i][1], acc[i][2], acc[i][3]);
    }
}

// ---------------------------------------------------------------------------
extern "C" void kernel_launch(void* const* d_in, const int* in_sizes, int n_in,
                              void* d_out, int out_size, void* d_ws, size_t ws_size,
                              hipStream_t stream)
{
    const float* query = (const float*)d_in[0];
    const float* key   = (const float*)d_in[1];
    const float* value = (const float*)d_in[2];
    const int*   mask  = (const int*)d_in[3];
    const float* w_q = (const float*)d_in[4];
    const float* b_q = (const float*)d_in[5];
    const float* w_k = (const float*)d_in[6];
    const float* b_k = (const float*)d_in[7];
    const float* w_v = (const float*)d_in[8];
    const float* b_v = (const float*)d_in[9];
    const float* w_o = (const float*)d_in[10];
    const float* b_o = (const float*)d_in[11];

    float* out  = (float*)d_out;                       // (B,S,D_MODEL)
    float* attn = (float*)d_out + (size_t)4194304;     // (B,H,S,S)

    float* qws  = (float*)d_ws;                        // (B,H,S,DK)
    float* kws  = qws + 4194304;
    float* vws  = kws + 4194304;
    float* ctxw = vws + 4194304;                       // (B,S,D_MODEL)

    dim3 gemm_grid(NDIM / 64, MDIM / 64);   // (16, 64)
    dim3 block(256);

    hipLaunchKernelGGL(gemm_nt_kernel, gemm_grid, block, 0, stream, query, w_q, b_q, qws, 1);
    hipLaunchKernelGGL(gemm_nt_kernel, gemm_grid, block, 0, stream, key,   w_k, b_k, kws, 1);
    hipLaunchKernelGGL(gemm_nt_kernel, gemm_grid, block, 0, stream, value, w_v, b_v, vws, 1);

    dim3 attn_grid(S_LEN / QT, NH, 2);      // (32, 16, 2)
    hipLaunchKernelGGL(attn_kernel, attn_grid, block, 0, stream, qws, kws, vws, mask, attn, ctxw);

    hipLaunchKernelGGL(gemm_nt_kernel, gemm_grid, block, 0, stream, ctxw, w_o, b_o, out, 0);
}

// Round 2
// 1650.677 us; speedup vs baseline: 7.0679x; 1.0802x over previous
//
#include <hip/hip_runtime.h>
#include <math.h>

// Problem constants (B=2, S=2048, D_MODEL=1024, H=16, DK=64)
#define MDIM 4096   // B*S rows
#define NDIM 1024
#define KDIM 1024
#define S_LEN 2048
#define NH 16
#define DK 64
#define KT 64
#define QT 64
#define NTILE (S_LEN / KT)   // 32

// ---------------------------------------------------------------------------
// GEMM NT: Y = A(M,K) @ W(N,K)^T + bias(N)
// 64x64 tile, BK=64, register-prefetch double-buffer, barrier per 64 kk.
// Staging: thread (srow=tid>>2, sc4=tid&3) loads 4 float4 along k from row
// srow (64B-coalesced per 4 lanes), scatters transposed into As[k][m]
// (2-way bank aliasing only). Inner loop identical to attn QK (proven 60+ TF).
// ---------------------------------------------------------------------------
__global__ __launch_bounds__(256, 4)
void gemm_nt_kernel(const float* __restrict__ A, const float* __restrict__ W,
                    const float* __restrict__ bias, float* __restrict__ Y,
                    int split_head)
{
    __shared__ float As[64][68];
    __shared__ float Ws[64][68];
    const int tid = threadIdx.x;
    const int m0 = blockIdx.y << 6;
    const int n0 = blockIdx.x << 6;
    const int tx = tid & 15;
    const int ty = tid >> 4;
    const int srow = tid >> 2;   // 0..63
    const int sc4  = tid & 3;

    const float4* asrc = (const float4*)(A + (size_t)(m0 + srow) * KDIM) + sc4;
    const float4* wsrc = (const float4*)(W + (size_t)(n0 + srow) * KDIM) + sc4;

    float4 ar[4], wr[4];
    #pragma unroll
    for (int i = 0; i < 4; i++) { ar[i] = asrc[i << 2]; wr[i] = wsrc[i << 2]; }

    float acc[4][4] = {};

    for (int k0 = 0; k0 < KDIM; k0 += 64) {
        __syncthreads();   // previous tile's LDS reads complete
        #pragma unroll
        for (int i = 0; i < 4; i++) {
            int d = (sc4 + (i << 2)) << 2;
            As[d + 0][srow] = ar[i].x; As[d + 1][srow] = ar[i].y;
            As[d + 2][srow] = ar[i].z; As[d + 3][srow] = ar[i].w;
            Ws[d + 0][srow] = wr[i].x; Ws[d + 1][srow] = wr[i].y;
            Ws[d + 2][srow] = wr[i].z; Ws[d + 3][srow] = wr[i].w;
        }
        __syncthreads();
        if (k0 + 64 < KDIM) {
            asrc += 16; wsrc += 16;
            #pragma unroll
            for (int i = 0; i < 4; i++) { ar[i] = asrc[i << 2]; wr[i] = wsrc[i << 2]; }
        }
        #pragma unroll 8
        for (int kk = 0; kk < 64; kk++) {
            float a[4], w[4];
            *(float4*)a = *(const float4*)&As[kk][ty << 2];
            *(float4*)w = *(const float4*)&Ws[kk][tx << 2];
            #pragma unroll
            for (int i = 0; i < 4; i++)
                #pragma unroll
                for (int j = 0; j < 4; j++)
                    acc[i][j] += a[i] * w[j];
        }
    }

    #pragma unroll
    for (int i = 0; i < 4; i++) {
        int m = m0 + (ty << 2) + i;
        #pragma unroll
        for (int j = 0; j < 4; j++) {
            int n = n0 + (tx << 2) + j;
            float val = acc[i][j] + bias[n];
            if (split_head) {
                int b = m >> 11, s = m & (S_LEN - 1);
                int h = n >> 6,  d = n & (DK - 1);
                Y[(((size_t)(b * NH + h) * S_LEN + s) << 6) + d] = val;
            } else {
                Y[(size_t)m * NDIM + n] = val;
            }
        }
    }
}

// ---------------------------------------------------------------------------
// Fused attention, no QK recompute: pass 1 computes QK, online (m,l), and
// SPILLS raw masked/scaled scores into the attn output buffer. Pass 2
// re-reads its own scores (same thread, same addresses), normalizes, writes
// final probs over them, and runs PV. LDS: pass 2 aliases Vs->Qs, Ps->Ks,
// so footprint is 2 x 64x68 = 34.8 KB -> 4 blocks/CU.
// ---------------------------------------------------------------------------
__global__ __launch_bounds__(256, 4)
void attn_kernel(const float* __restrict__ q, const float* __restrict__ k,
                 const float* __restrict__ v, const int* __restrict__ mask,
                 float* __restrict__ attn, float* __restrict__ ctx)
{
    const int b   = blockIdx.z;
    const int h   = blockIdx.y;
    const int q0  = blockIdx.x << 6;
    const int tid = threadIdx.x;
    const int tx  = tid & 15;
    const int ty  = tid >> 4;

    __shared__ float Qs[64][68];   // pass2: aliased as Vs[kk][d]
    __shared__ float Ks[64][68];   // pass2: aliased as Ps[kk][m]
    float (*Vs)[68] = Qs;
    float* Ps = &Ks[0][0];

    const float* qbase = q + (((size_t)(b * NH + h) * S_LEN + q0) << 6);
    const float* kbase = k + (((size_t)(b * NH + h) * S_LEN) << 6);
    const float* vbase = v + (((size_t)(b * NH + h) * S_LEN) << 6);
    const int*   mrow  = mask + b * S_LEN;

    const int srow = tid >> 2;   // 0..63 staging row
    const int sc4  = tid & 3;

    // ---- stage Q transposed: Qs[d][m] ----
    {
        const float4* src = (const float4*)(qbase + ((size_t)srow << 6)) + sc4;
        #pragma unroll
        for (int i = 0; i < 4; i++) {
            float4 t = src[i << 2];
            int d = (sc4 + (i << 2)) << 2;
            Qs[d + 0][srow] = t.x; Qs[d + 1][srow] = t.y;
            Qs[d + 2][srow] = t.z; Qs[d + 3][srow] = t.w;
        }
    }

    const float scale = 0.125f;   // 1/sqrt(64)
    float mr[4], lr[4];
    #pragma unroll
    for (int i = 0; i < 4; i++) { mr[i] = -1e30f; lr[i] = 0.f; }

    const size_t abase = ((size_t)((b * NH + h) * S_LEN + q0 + (ty << 2))) * S_LEN
                       + (tx << 2);

    // ==================== pass 1: QK + stats + score spill ====================
    const float4* ksrc = (const float4*)(kbase + ((size_t)srow << 6)) + sc4;
    float4 kr[4];
    #pragma unroll
    for (int i = 0; i < 4; i++) kr[i] = ksrc[i << 2];

    for (int t = 0; t < NTILE; t++) {
        __syncthreads();   // prev tile's Ks reads done (t=0: Qs staged)
        #pragma unroll
        for (int i = 0; i < 4; i++) {
            int d = (sc4 + (i << 2)) << 2;
            Ks[d + 0][srow] = kr[i].x; Ks[d + 1][srow] = kr[i].y;
            Ks[d + 2][srow] = kr[i].z; Ks[d + 3][srow] = kr[i].w;
        }
        __syncthreads();
        if (t + 1 < NTILE) {
            ksrc += 1024;   // next 64 rows x 16 float4
            #pragma unroll
            for (int i = 0; i < 4; i++) kr[i] = ksrc[i << 2];
        }

        float s[4][4] = {};
        #pragma unroll 8
        for (int kk = 0; kk < 64; kk++) {
            float a[4], w[4];
            *(float4*)a = *(const float4*)&Qs[kk][ty << 2];
            *(float4*)w = *(const float4*)&Ks[kk][tx << 2];
            #pragma unroll
            for (int i = 0; i < 4; i++)
                #pragma unroll
                for (int j = 0; j < 4; j++)
                    s[i][j] += a[i] * w[j];
        }

        int4 mk = ((const int4*)(mrow + (t << 6)))[tx];
        #pragma unroll
        for (int i = 0; i < 4; i++) {
            s[i][0] = (mk.x == 0) ? -1e9f : s[i][0] * scale;
            s[i][1] = (mk.y == 0) ? -1e9f : s[i][1] * scale;
            s[i][2] = (mk.z == 0) ? -1e9f : s[i][2] * scale;
            s[i][3] = (mk.w == 0) ? -1e9f : s[i][3] * scale;
            float mt = fmaxf(fmaxf(s[i][0], s[i][1]), fmaxf(s[i][2], s[i][3]));
            float mn = fmaxf(mr[i], mt);
            lr[i] = lr[i] * __expf(mr[i] - mn)
                  + __expf(s[i][0] - mn) + __expf(s[i][1] - mn)
                  + __expf(s[i][2] - mn) + __expf(s[i][3] - mn);
            mr[i] = mn;
            // spill raw masked/scaled scores (overwritten with probs in pass 2)
            *(float4*)(attn + abase + (t << 6) + (size_t)i * S_LEN) =
                make_float4(s[i][0], s[i][1], s[i][2], s[i][3]);
        }
    }

    // combine across the 16 column-lanes (consecutive lanes, same wave)
    #pragma unroll
    for (int off = 1; off < 16; off <<= 1) {
        #pragma unroll
        for (int i = 0; i < 4; i++) {
            float m2 = __shfl_xor(mr[i], off);
            float l2 = __shfl_xor(lr[i], off);
            float mn = fmaxf(mr[i], m2);
            lr[i] = lr[i] * __expf(mr[i] - mn) + l2 * __expf(m2 - mn);
            mr[i] = mn;
        }
    }
    float invl[4];
    #pragma unroll
    for (int i = 0; i < 4; i++) invl[i] = 1.0f / lr[i];

    // ==================== pass 2: normalize + PV ====================
    const int vrow = tid >> 4;   // + 16*i
    const int vc4  = tid & 15;

    float acc[4][4] = {};
    float4 vr[4], sr[4];
    #pragma unroll
    for (int i = 0; i < 4; i++) {
        vr[i] = ((const float4*)(vbase + (((size_t)(vrow + (i << 4))) << 6)))[vc4];
        sr[i] = *(const float4*)(attn + abase + (size_t)i * S_LEN);
    }

    for (int t = 0; t < NTILE; t++) {
        __syncthreads();   // prev tile's Ps/Vs reads done (t=0: pass1 reads done)
        #pragma unroll
        for (int i = 0; i < 4; i++)
            *(float4*)&Vs[vrow + (i << 4)][vc4 << 2] = vr[i];

        float p[4][4];
        #pragma unroll
        for (int i = 0; i < 4; i++) {
            p[i][0] = __expf(sr[i].x - mr[i]) * invl[i];
            p[i][1] = __expf(sr[i].y - mr[i]) * invl[i];
            p[i][2] = __expf(sr[i].z - mr[i]) * invl[i];
            p[i][3] = __expf(sr[i].w - mr[i]) * invl[i];
            *(float4*)(attn + abase + (t << 6) + (size_t)i * S_LEN) =
                make_float4(p[i][0], p[i][1], p[i][2], p[i][3]);
        }
        #pragma unroll
        for (int j = 0; j < 4; j++)
            *(float4*)&Ps[(size_t)((tx << 2) + j) * 68 + (ty << 2)] =
                make_float4(p[0][j], p[1][j], p[2][j], p[3][j]);
        __syncthreads();

        if (t + 1 < NTILE) {
            #pragma unroll
            for (int i = 0; i < 4; i++) {
                vr[i] = ((const float4*)(vbase +
                          ((((size_t)(t + 1) << 6) + vrow + (i << 4)) << 6)))[vc4];
                sr[i] = *(const float4*)(attn + abase + ((t + 1) << 6)
                                         + (size_t)i * S_LEN);
            }
        }

        #pragma unroll 8
        for (int kk = 0; kk < 64; kk++) {
            float pa[4], wv[4];
            *(float4*)pa = *(const float4*)&Ps[(size_t)kk * 68 + (ty << 2)];
            *(float4*)wv = *(const float4*)&Vs[kk][tx << 2];
            #pragma unroll
            for (int i = 0; i < 4; i++)
                #pragma unroll
                for (int j = 0; j < 4; j++)
                    acc[i][j] += pa[i] * wv[j];
        }
    }

    // ctx write, (B, S, H, DK) layout
    #pragma unroll
    for (int i = 0; i < 4; i++) {
        int row = q0 + (ty << 2) + i;
        *(float4*)(ctx + (((size_t)(b * S_LEN + row) * NH + h) << 6) + (tx << 2)) =
            make_float4(acc[i][0], acc[i][1], acc[i][2], acc[i][3]);
    }
}

// ---------------------------------------------------------------------------
extern "C" void kernel_launch(void* const* d_in, const int* in_sizes, int n_in,
                              void* d_out, int out_size, void* d_ws, size_t ws_size,
                              hipStream_t stream)
{
    const float* query = (const float*)d_in[0];
    const float* key   = (const float*)d_in[1];
    const float* value = (const float*)d_in[2];
    const int*   mask  = (const int*)d_in[3];
    const float* w_q = (const float*)d_in[4];
    const float* b_q = (const float*)d_in[5];
    const float* w_k = (const float*)d_in[6];
    const float* b_k = (const float*)d_in[7];
    const float* w_v = (const float*)d_in[8];
    const float* b_v = (const float*)d_in[9];
    const float* w_o = (const float*)d_in[10];
    const float* b_o = (const float*)d_in[11];

    float* out  = (float*)d_out;                       // (B,S,D_MODEL)
    float* attn = (float*)d_out + (size_t)4194304;     // (B,H,S,S)

    float* qws  = (float*)d_ws;                        // (B,H,S,DK)
    float* kws  = qws + 4194304;
    float* vws  = kws + 4194304;
    float* ctxw = vws + 4194304;                       // (B,S,D_MODEL)

    dim3 gemm_grid(NDIM / 64, MDIM / 64);   // (16, 64)
    dim3 block(256);

    hipLaunchKernelGGL(gemm_nt_kernel, gemm_grid, block, 0, stream, query, w_q, b_q, qws, 1);
    hipLaunchKernelGGL(gemm_nt_kernel, gemm_grid, block, 0, stream, key,   w_k, b_k, kws, 1);
    hipLaunchKernelGGL(gemm_nt_kernel, gemm_grid, block, 0, stream, value, w_v, b_v, vws, 1);

    dim3 attn_grid(S_LEN / QT, NH, 2);      // (32, 16, 2)
    hipLaunchKernelGGL(attn_kernel, attn_grid, block, 0, stream, qws, kws, vws, mask, attn, ctxw);

    hipLaunchKernelGGL(gemm_nt_kernel, gemm_grid, block, 0, stream, ctxw, w_o, b_o, out, 0);
}